// Round 4
// baseline (276.684 us; speedup 1.0000x reference)
//
#include <hip/hip_runtime.h>

// Fused Haar DWT (2x2) + 2x bilinear upsample (jax.image.resize half-pixel
// convention == clamped stencil: out[2k]=.25 t[k-1]+.75 t[k], out[2k+1]=.75 t[k]+.25 t[k+1]).
//
// Input  x: [8][64][256][256] f32
// Output: up(ll) [8][64][256][256], then concat([up(lh),up(hl),up(hh)],axis=1) [8][192][256][256]
//
// One block = one 64x64 output tile of one (n,c) plane.
// Step 1: 34x34 subband halo tiles in LDS (68x68 input patch, float2 loads, cached).
// Step 2: each thread produces 8 consecutive outputs per subband row via
//         ds_read_b128+ds_read_b64 (4x fewer LDS instrs than scalar), writes
//         2x float4 NONTEMPORAL stores (output streamed once, no L2/L3 alloc).

typedef float f32x4 __attribute__((ext_vector_type(4)));
typedef float f32x2 __attribute__((ext_vector_type(2)));

__global__ __launch_bounds__(256) void haar_dwt_up_kernel(
    const float* __restrict__ x, float* __restrict__ out)
{
  const int plane = blockIdx.y;       // n*64 + c, 0..511
  const int ty = blockIdx.x >> 2;     // 4x4 tiles of 64x64
  const int tx = blockIdx.x & 3;
  const int tid = threadIdx.x;

  __shared__ float sLL[34][36];
  __shared__ float sLH[34][36];
  __shared__ float sHL[34][36];
  __shared__ float sHH[34][36];

  const float* __restrict__ xp = x + (size_t)plane * 65536u;
  const int kY0 = ty * 32 - 1;        // subband-space tile origin (with -1 halo)
  const int kX0 = tx * 32 - 1;

  // ---- Step 1: subband tiles into LDS ----
  for (int cidx = tid; cidx < 34 * 34; cidx += 256) {
    const int i  = cidx / 34;
    const int jj = cidx - i * 34;
    int k = kY0 + i;  k = k < 0 ? 0 : (k > 127 ? 127 : k);
    int j = kX0 + jj; j = j < 0 ? 0 : (j > 127 ? 127 : j);
    const float2 r0 = *reinterpret_cast<const float2*>(xp + (size_t)(2 * k) * 256 + 2 * j);
    const float2 r1 = *reinterpret_cast<const float2*>(xp + (size_t)(2 * k + 1) * 256 + 2 * j);
    const float a = r0.x, b = r0.y, c = r1.x, d = r1.y;
    sLL[i][jj] = 0.5f * (a + b + c + d);
    sLH[i][jj] = 0.5f * (c + d - a - b);
    sHL[i][jj] = 0.5f * (b + d - a - c);
    sHH[i][jj] = 0.5f * (a + d - b - c);
  }
  __syncthreads();

  // ---- Step 2: 8-wide upsample windows, vector LDS reads, nt stores ----
  const int n = plane >> 6;
  const int c = plane & 63;
  float* __restrict__ oLL = out + (size_t)plane * 65536u;
  float* __restrict__ oLH = out + 33554432u + (size_t)(n * 192 + c) * 65536u;
  float* __restrict__ oHL = oLH + (size_t)64 * 65536u;
  float* __restrict__ oHH = oLH + (size_t)128 * 65536u;

#pragma unroll
  for (int it = 0; it < 2; ++it) {
    const int p    = tid + it * 256;     // 0..511: 64 rows x 8 chunks-of-8
    const int orow = p >> 3;
    const int m    = p & 7;
    const int li   = (orow >> 1) + 1;    // local subband row (halo offset +1)
    const int ry   = orow & 1;
    const int rA   = ry ? li     : li - 1;
    const int rB   = ry ? li + 1 : li;
    const float wA = ry ? 0.75f : 0.25f;
    const float wB = ry ? 0.25f : 0.75f;
    const int c4   = 4 * m;              // local subband col window base (needs c4..c4+5)
    const size_t off = (size_t)(ty * 64 + orow) * 256 + (size_t)(tx * 64 + 8 * m);

    // v0..v5 = vertically-interpolated subband values at local cols c4..c4+5
    // out col 8m+c: even c -> .25 v[(c>>1)] + .75 v[(c>>1)+1]; odd mirrors.
#define EMIT8(S, DST)                                                          \
    {                                                                          \
      const f32x4 A0 = *reinterpret_cast<const f32x4*>(&S[rA][c4]);            \
      const f32x2 A1 = *reinterpret_cast<const f32x2*>(&S[rA][c4 + 4]);        \
      const f32x4 B0 = *reinterpret_cast<const f32x4*>(&S[rB][c4]);            \
      const f32x2 B1 = *reinterpret_cast<const f32x2*>(&S[rB][c4 + 4]);        \
      const f32x4 Vl = wA * A0 + wB * B0;                                      \
      const f32x2 Vh = wA * A1 + wB * B1;                                      \
      f32x4 o0, o1;                                                            \
      o0.x = 0.25f * Vl.x + 0.75f * Vl.y;                                      \
      o0.y = 0.75f * Vl.y + 0.25f * Vl.z;                                      \
      o0.z = 0.25f * Vl.y + 0.75f * Vl.z;                                      \
      o0.w = 0.75f * Vl.z + 0.25f * Vl.w;                                      \
      o1.x = 0.25f * Vl.z + 0.75f * Vl.w;                                      \
      o1.y = 0.75f * Vl.w + 0.25f * Vh.x;                                      \
      o1.z = 0.25f * Vl.w + 0.75f * Vh.x;                                      \
      o1.w = 0.75f * Vh.x + 0.25f * Vh.y;                                      \
      __builtin_nontemporal_store(o0, reinterpret_cast<f32x4*>((DST) + off));     \
      __builtin_nontemporal_store(o1, reinterpret_cast<f32x4*>((DST) + off + 4)); \
    }

    EMIT8(sLL, oLL)
    EMIT8(sLH, oLH)
    EMIT8(sHL, oHL)
    EMIT8(sHH, oHH)
#undef EMIT8
  }
}

extern "C" void kernel_launch(void* const* d_in, const int* in_sizes, int n_in,
                              void* d_out, int out_size, void* d_ws, size_t ws_size,
                              hipStream_t stream) {
  const float* x = (const float*)d_in[0];
  float* out = (float*)d_out;
  dim3 grid(16, 512);   // 4x4 tiles x (8*64 planes)
  haar_dwt_up_kernel<<<grid, 256, 0, stream>>>(x, out);
}

// Round 5
// 119.723 us; speedup vs baseline: 2.3110x; 2.3110x over previous
//
#include <hip/hip_runtime.h>

// Fused Haar DWT (2x2) + 2x bilinear upsample (jax.image.resize half-pixel
// convention == clamped stencil: out[2k]=.25 t[k-1]+.75 t[k], out[2k+1]=.75 t[k]+.25 t[k+1]).
//
// Input  x: [8][64][256][256] f32
// Output: up(ll) [8][64][256][256], then concat([up(lh),up(hl),up(hh)],axis=1) [8][192][256][256]
//
// One block = one 64x64 output tile of one (n,c) plane.
// Step 1: 34x34 subband halo tiles in LDS (68x68 input patch, float2 loads, cached).
// Step 2: round-3 layout (one float4 nt store per thread per EMIT — 64 lanes x 16B
//         fully contiguous per store instruction; round 4 showed 32B-stride lane
//         gaps + nt stores = 2.3x regression). LDS reads vectorized to 4x b64
//         per EMIT (8B aligned: row stride 144B, col offset 8m B).

typedef float f32x4 __attribute__((ext_vector_type(4)));
typedef float f32x2 __attribute__((ext_vector_type(2)));

__global__ __launch_bounds__(256) void haar_dwt_up_kernel(
    const float* __restrict__ x, float* __restrict__ out)
{
  const int plane = blockIdx.y;       // n*64 + c, 0..511
  const int ty = blockIdx.x >> 2;     // 4x4 tiles of 64x64
  const int tx = blockIdx.x & 3;
  const int tid = threadIdx.x;

  __shared__ float sLL[34][36];
  __shared__ float sLH[34][36];
  __shared__ float sHL[34][36];
  __shared__ float sHH[34][36];

  const float* __restrict__ xp = x + (size_t)plane * 65536u;
  const int kY0 = ty * 32 - 1;        // subband-space tile origin (with -1 halo)
  const int kX0 = tx * 32 - 1;

  // ---- Step 1: subband tiles into LDS ----
  for (int cidx = tid; cidx < 34 * 34; cidx += 256) {
    const int i  = cidx / 34;
    const int jj = cidx - i * 34;
    int k = kY0 + i;  k = k < 0 ? 0 : (k > 127 ? 127 : k);
    int j = kX0 + jj; j = j < 0 ? 0 : (j > 127 ? 127 : j);
    const float2 r0 = *reinterpret_cast<const float2*>(xp + (size_t)(2 * k) * 256 + 2 * j);
    const float2 r1 = *reinterpret_cast<const float2*>(xp + (size_t)(2 * k + 1) * 256 + 2 * j);
    const float a = r0.x, b = r0.y, c = r1.x, d = r1.y;
    sLL[i][jj] = 0.5f * (a + b + c + d);
    sLH[i][jj] = 0.5f * (c + d - a - b);
    sHL[i][jj] = 0.5f * (b + d - a - c);
    sHH[i][jj] = 0.5f * (a + d - b - c);
  }
  __syncthreads();

  // ---- Step 2: bilinear 2x upsample from LDS, 4 subbands, nt stores ----
  const int n = plane >> 6;
  const int c = plane & 63;
  float* __restrict__ oLL = out + (size_t)plane * 65536u;
  float* __restrict__ oLH = out + 33554432u + (size_t)(n * 192 + c) * 65536u;
  float* __restrict__ oHL = oLH + (size_t)64 * 65536u;
  float* __restrict__ oHH = oLH + (size_t)128 * 65536u;

#pragma unroll
  for (int it = 0; it < 4; ++it) {
    const int p    = tid + it * 256;     // 0..1023 float4 slots in 64x64 tile
    const int orow = p >> 4;             // 16 float4s per output row
    const int m    = p & 15;
    const int li   = (orow >> 1) + 1;    // local subband row (halo offset +1)
    const int ry   = orow & 1;
    const int rA   = ry ? li     : li - 1;
    const int rB   = ry ? li + 1 : li;
    const float wA = ry ? 0.75f : 0.25f;
    const float wB = ry ? 0.25f : 0.75f;
    const int cj   = 2 * m;              // local subband col window base (2m..2m+3)
    const size_t off = (size_t)(ty * 64 + orow) * 256 + (size_t)(tx * 64 + 4 * m);

#define EMIT(S, DST)                                                   \
    {                                                                  \
      const f32x2 a0 = *reinterpret_cast<const f32x2*>(&S[rA][cj]);    \
      const f32x2 a1 = *reinterpret_cast<const f32x2*>(&S[rA][cj+2]);  \
      const f32x2 b0 = *reinterpret_cast<const f32x2*>(&S[rB][cj]);    \
      const f32x2 b1 = *reinterpret_cast<const f32x2*>(&S[rB][cj+2]);  \
      const float v0 = wA * a0.x + wB * b0.x;                          \
      const float v1 = wA * a0.y + wB * b0.y;                          \
      const float v2 = wA * a1.x + wB * b1.x;                          \
      const float v3 = wA * a1.y + wB * b1.y;                          \
      f32x4 o;                                                         \
      o.x = 0.25f * v0 + 0.75f * v1;                                   \
      o.y = 0.75f * v1 + 0.25f * v2;                                   \
      o.z = 0.25f * v1 + 0.75f * v2;                                   \
      o.w = 0.75f * v2 + 0.25f * v3;                                   \
      __builtin_nontemporal_store(o, reinterpret_cast<f32x4*>((DST) + off)); \
    }

    EMIT(sLL, oLL)
    EMIT(sLH, oLH)
    EMIT(sHL, oHL)
    EMIT(sHH, oHH)
#undef EMIT
  }
}

extern "C" void kernel_launch(void* const* d_in, const int* in_sizes, int n_in,
                              void* d_out, int out_size, void* d_ws, size_t ws_size,
                              hipStream_t stream) {
  const float* x = (const float*)d_in[0];
  float* out = (float*)d_out;
  dim3 grid(16, 512);   // 4x4 tiles x (8*64 planes)
  haar_dwt_up_kernel<<<grid, 256, 0, stream>>>(x, out);
}

// Round 6
// 107.607 us; speedup vs baseline: 2.5712x; 1.1126x over previous
//
#include <hip/hip_runtime.h>

// Fused Haar DWT (2x2) + 2x bilinear upsample (jax.image.resize half-pixel
// convention == clamped stencil: out[2k]=.25 t[k-1]+.75 t[k], out[2k+1]=.75 t[k]+.25 t[k+1]).
//
// Input  x: [8][64][256][256] f32
// Output: up(ll) [8][64][256][256], then concat([up(lh),up(hl),up(hh)],axis=1) [8][192][256][256]
//
// Round 6: full-width slabs. One block = 32 output rows x 256 cols of one plane.
//  - Subband halo tile: 18 rows x 130 cols (y halo only; x halo is edge-clamp, no extra fetch).
//  - Step 2 store: each nt-store instruction = 64 lanes x 16B = ONE contiguous 1KB output row
//    (round-5 64-wide tiles gave 4x 256B chunks per instr; testing store contiguity).

typedef float f32x4 __attribute__((ext_vector_type(4)));
typedef float f32x2 __attribute__((ext_vector_type(2)));

__global__ __launch_bounds__(256) void haar_dwt_up_kernel(
    const float* __restrict__ x, float* __restrict__ out)
{
  const int plane = blockIdx.y;       // n*64 + c, 0..511
  const int slab  = blockIdx.x;       // 8 slabs of 32 output rows
  const int tid   = threadIdx.x;

  __shared__ float sLL[18][132];
  __shared__ float sLH[18][132];
  __shared__ float sHL[18][132];
  __shared__ float sHH[18][132];

  const float* __restrict__ xp = x + (size_t)plane * 65536u;
  const int kY0 = slab * 16 - 1;      // subband-space slab origin (with -1 y halo)

  // ---- Step 1: 18x130 subband slab into LDS ----
  for (int cidx = tid; cidx < 18 * 130; cidx += 256) {
    const int i  = cidx / 130;
    const int jj = cidx - i * 130;
    int k = kY0 + i;  k = k < 0 ? 0 : (k > 127 ? 127 : k);
    int j = jj - 1;   j = j < 0 ? 0 : (j > 127 ? 127 : j);
    const float2 r0 = *reinterpret_cast<const float2*>(xp + (size_t)(2 * k) * 256 + 2 * j);
    const float2 r1 = *reinterpret_cast<const float2*>(xp + (size_t)(2 * k + 1) * 256 + 2 * j);
    const float a = r0.x, b = r0.y, c = r1.x, d = r1.y;
    sLL[i][jj] = 0.5f * (a + b + c + d);
    sLH[i][jj] = 0.5f * (c + d - a - b);
    sHL[i][jj] = 0.5f * (b + d - a - c);
    sHH[i][jj] = 0.5f * (a + d - b - c);
  }
  __syncthreads();

  // ---- Step 2: bilinear 2x upsample, full-row contiguous nt stores ----
  const int n = plane >> 6;
  const int c = plane & 63;
  float* __restrict__ oLL = out + (size_t)plane * 65536u;
  float* __restrict__ oLH = out + 33554432u + (size_t)(n * 192 + c) * 65536u;
  float* __restrict__ oHL = oLH + (size_t)64 * 65536u;
  float* __restrict__ oHH = oLH + (size_t)128 * 65536u;

#pragma unroll
  for (int it = 0; it < 8; ++it) {
    const int p    = tid + it * 256;     // 0..2047: 32 rows x 64 float4/row
    const int orow = p >> 6;
    const int m    = p & 63;             // float4 index within the row
    const int li   = (orow >> 1) + 1;    // local subband row (halo offset +1)
    const int ry   = orow & 1;
    const int rA   = ry ? li     : li - 1;
    const int rB   = ry ? li + 1 : li;
    const float wA = ry ? 0.75f : 0.25f;
    const float wB = ry ? 0.25f : 0.75f;
    const int cj   = 2 * m;              // local subband col window base (2m..2m+3)
    const size_t off = (size_t)(slab * 32 + orow) * 256 + (size_t)(4 * m);

#define EMIT(S, DST)                                                   \
    {                                                                  \
      const f32x2 a0 = *reinterpret_cast<const f32x2*>(&S[rA][cj]);    \
      const f32x2 a1 = *reinterpret_cast<const f32x2*>(&S[rA][cj+2]);  \
      const f32x2 b0 = *reinterpret_cast<const f32x2*>(&S[rB][cj]);    \
      const f32x2 b1 = *reinterpret_cast<const f32x2*>(&S[rB][cj+2]);  \
      const float v0 = wA * a0.x + wB * b0.x;                          \
      const float v1 = wA * a0.y + wB * b0.y;                          \
      const float v2 = wA * a1.x + wB * b1.x;                          \
      const float v3 = wA * a1.y + wB * b1.y;                          \
      f32x4 o;                                                         \
      o.x = 0.25f * v0 + 0.75f * v1;                                   \
      o.y = 0.75f * v1 + 0.25f * v2;                                   \
      o.z = 0.25f * v1 + 0.75f * v2;                                   \
      o.w = 0.75f * v2 + 0.25f * v3;                                   \
      __builtin_nontemporal_store(o, reinterpret_cast<f32x4*>((DST) + off)); \
    }

    EMIT(sLL, oLL)
    EMIT(sLH, oLH)
    EMIT(sHL, oHL)
    EMIT(sHH, oHH)
#undef EMIT
  }
}

extern "C" void kernel_launch(void* const* d_in, const int* in_sizes, int n_in,
                              void* d_out, int out_size, void* d_ws, size_t ws_size,
                              hipStream_t stream) {
  const float* x = (const float*)d_in[0];
  float* out = (float*)d_out;
  dim3 grid(8, 512);   // 8 row-slabs x (8*64 planes)
  haar_dwt_up_kernel<<<grid, 256, 0, stream>>>(x, out);
}